// Round 2
// baseline (1085.037 us; speedup 1.0000x reference)
//
#include <hip/hip_runtime.h>
#include <hip/hip_bf16.h>
#include <math.h>

#define N_NODES 100000
#define N_EDGES 1600000
#define F_IN 128
#define F_HID 128
#define N_CLS 16

// ---------------- degree / dis ----------------

__global__ __launch_bounds__(256) void deg_init_kernel(float* __restrict__ deg) {
    int i = blockIdx.x * 256 + threadIdx.x;
    if (i < N_NODES) deg[i] = 1.0f;  // self-loop contributes 1
}

__global__ __launch_bounds__(256) void deg_count_kernel(const int* __restrict__ dst,
                                                        float* __restrict__ deg) {
    int e = blockIdx.x * 256 + threadIdx.x;
    if (e < N_EDGES) unsafeAtomicAdd(&deg[dst[e]], 1.0f);
}

__global__ __launch_bounds__(256) void dis_kernel(float* __restrict__ deg) {
    int i = blockIdx.x * 256 + threadIdx.x;
    if (i < N_NODES) deg[i] = rsqrtf(deg[i]);  // deg >= 1 (self-loop), exact int sums
}

// ---------------- xa seed: xa[i] = x[i] * dis[i]^2 (self-loop term) ----------------

__global__ __launch_bounds__(256) void xa_init_kernel(const float* __restrict__ x,
                                                      const float* __restrict__ dis,
                                                      float* __restrict__ xa) {
    int idx = blockIdx.x * 256 + threadIdx.x;     // one float4 per thread; 3.2M total
    int node = idx >> 5;                          // 32 float4 per node row
    float d = dis[node];
    float d2 = d * d;
    float4 v = *(const float4*)&x[idx * 4];
    *(float4*)&xa[idx * 4] = make_float4(v.x * d2, v.y * d2, v.z * d2, v.w * d2);
}

// ---------------- scatter layer 1: xa[dst] += x[src] * dis[src]*dis[dst] ----------------
// 128 consecutive threads per edge (2 waves, wave-uniform src/dst).

__global__ __launch_bounds__(256) void scatter_x_kernel(const int* __restrict__ src,
                                                        const int* __restrict__ dst,
                                                        const float* __restrict__ dis,
                                                        const float* __restrict__ x,
                                                        float* __restrict__ xa) {
    int idx = blockIdx.x * 256 + threadIdx.x;   // < 204,800,000 fits int32
    int e = idx >> 7;
    int f = idx & 127;
    int s = src[e], d = dst[e];
    float w = dis[s] * dis[d];
    float v = x[s * 128 + f] * w;
    unsafeAtomicAdd(&xa[d * 128 + f], v);
}

// ---------------- GEMM1 (in-place): xa = relu(xa @ W1 + b1) ----------------
// BM=32, BN=128, BK=32; 256 threads, 4x4 micro-tile each.
// In-place safe: block reads only its own 32 rows (all reads before epilogue writes).

__global__ __launch_bounds__(256) void gemm1_kernel(float* __restrict__ xa,
                                                    const float* __restrict__ W,
                                                    const float* __restrict__ b1) {
    __shared__ float As[32][32];    // 4 KB
    __shared__ float Bs[32][128];   // 16 KB
    const int t = threadIdx.x;
    const int m0 = blockIdx.x * 32;         // 3125 blocks * 32 = 100000 exact
    const int tc = t & 31;                  // col group: 32 * 4 = 128 cols
    const int tr = t >> 5;                  // row group: 8 * 4 = 32 rows
    float acc[4][4] = {};

    for (int kb = 0; kb < 128; kb += 32) {
        {   // stage A tile: 32x32 floats = 256 float4, one per thread
            int row = t >> 3, col = (t & 7) << 2;
            *(float4*)&As[row][col] = *(const float4*)&xa[(m0 + row) * 128 + kb + col];
        }
        #pragma unroll
        for (int i = 0; i < 4; i++) {   // stage B tile: 32x128 = 1024 float4
            int p = t + i * 256;
            int row = p >> 5, col = (p & 31) << 2;
            *(float4*)&Bs[row][col] = *(const float4*)&W[(kb + row) * 128 + col];
        }
        __syncthreads();
        #pragma unroll
        for (int k = 0; k < 32; k += 4) {
            float4 av[4], bv[4];
            #pragma unroll
            for (int i = 0; i < 4; i++) av[i] = *(const float4*)&As[tr * 4 + i][k];
            #pragma unroll
            for (int j = 0; j < 4; j++) bv[j] = *(const float4*)&Bs[k + j][tc * 4];
            #pragma unroll
            for (int i = 0; i < 4; i++) {
                acc[i][0] += av[i].x * bv[0].x + av[i].y * bv[1].x + av[i].z * bv[2].x + av[i].w * bv[3].x;
                acc[i][1] += av[i].x * bv[0].y + av[i].y * bv[1].y + av[i].z * bv[2].y + av[i].w * bv[3].y;
                acc[i][2] += av[i].x * bv[0].z + av[i].y * bv[1].z + av[i].z * bv[2].z + av[i].w * bv[3].z;
                acc[i][3] += av[i].x * bv[0].w + av[i].y * bv[1].w + av[i].z * bv[2].w + av[i].w * bv[3].w;
            }
        }
        __syncthreads();
    }
    float4 bb = *(const float4*)&b1[tc * 4];
    #pragma unroll
    for (int i = 0; i < 4; i++) {
        int m = m0 + tr * 4 + i;
        *(float4*)&xa[m * 128 + tc * 4] = make_float4(fmaxf(acc[i][0] + bb.x, 0.0f),
                                                      fmaxf(acc[i][1] + bb.y, 0.0f),
                                                      fmaxf(acc[i][2] + bb.z, 0.0f),
                                                      fmaxf(acc[i][3] + bb.w, 0.0f));
    }
}

// ---------------- GEMM2: h2 = xa @ W2 (K=128, N=16); out seeded with h2*dis^2 ----------------

__global__ __launch_bounds__(256) void gemm2_kernel(const float* __restrict__ xa,
                                                    const float* __restrict__ W2,
                                                    const float* __restrict__ dis,
                                                    float* __restrict__ h2,
                                                    float* __restrict__ out) {
    __shared__ float As[16][132];   // +4 pad breaks the 128-float same-bank stride
    __shared__ float Ws[128][16];
    const int t = threadIdx.x;
    const int m0 = blockIdx.x * 16;             // 6250 * 16 = 100000 exact

    #pragma unroll
    for (int i = 0; i < 2; i++) {   // stage W2: 2048 floats = 512 float4
        int p = t + i * 256;
        int row = p >> 2, col = (p & 3) << 2;
        *(float4*)&Ws[row][col] = *(const float4*)&W2[row * 16 + col];
    }
    #pragma unroll
    for (int i = 0; i < 2; i++) {   // stage A tile: 16x128 = 512 float4
        int p = t + i * 256;
        int row = p >> 5, col = (p & 31) << 2;
        *(float4*)&As[row][col] = *(const float4*)&xa[(m0 + row) * 128 + col];
    }
    __syncthreads();

    const int ml = t >> 4, n = t & 15;
    float acc = 0.0f;
    #pragma unroll
    for (int k = 0; k < 128; k += 4) {
        float4 a = *(const float4*)&As[ml][k];
        acc += a.x * Ws[k][n] + a.y * Ws[k + 1][n] + a.z * Ws[k + 2][n] + a.w * Ws[k + 3][n];
    }
    int m = m0 + ml;
    float d = dis[m];
    h2[m * 16 + n] = acc;
    out[m * 16 + n] = acc * d * d;
}

// ---------------- scatter layer 2: out[dst] += h2[src] * dis[src]*dis[dst] ----------------

__global__ __launch_bounds__(256) void scatter2_kernel(const int* __restrict__ src,
                                                       const int* __restrict__ dst,
                                                       const float* __restrict__ dis,
                                                       const float* __restrict__ h2,
                                                       float* __restrict__ out) {
    int idx = blockIdx.x * 256 + threadIdx.x;   // < 25,600,000
    int e = idx >> 4;
    int f = idx & 15;
    int s = src[e], d = dst[e];
    float w = dis[s] * dis[d];
    float v = h2[s * 16 + f] * w;
    unsafeAtomicAdd(&out[d * 16 + f], v);
}

// ---------------- final: out = log_softmax(out + b2) ----------------

__global__ __launch_bounds__(256) void lsm_kernel(const float* __restrict__ b2,
                                                  float* __restrict__ out) {
    int i = blockIdx.x * 256 + threadIdx.x;
    if (i >= N_NODES) return;
    float v[16];
    #pragma unroll
    for (int j = 0; j < 4; j++) {
        float4 a = *(const float4*)&out[i * 16 + j * 4];
        float4 bb = *(const float4*)&b2[j * 4];
        v[j * 4 + 0] = a.x + bb.x;
        v[j * 4 + 1] = a.y + bb.y;
        v[j * 4 + 2] = a.z + bb.z;
        v[j * 4 + 3] = a.w + bb.w;
    }
    float m = v[0];
    #pragma unroll
    for (int j = 1; j < 16; j++) m = fmaxf(m, v[j]);
    float s = 0.0f;
    #pragma unroll
    for (int j = 0; j < 16; j++) s += expf(v[j] - m);
    float l = m + logf(s);
    #pragma unroll
    for (int j = 0; j < 4; j++) {
        *(float4*)&out[i * 16 + j * 4] =
            make_float4(v[4 * j] - l, v[4 * j + 1] - l, v[4 * j + 2] - l, v[4 * j + 3] - l);
    }
}

// ---------------- launch ----------------

extern "C" void kernel_launch(void* const* d_in, const int* in_sizes, int n_in,
                              void* d_out, int out_size, void* d_ws, size_t ws_size,
                              hipStream_t stream) {
    const float* x  = (const float*)d_in[0];
    const int*   ei = (const int*)d_in[1];     // int32 per harness contract
    const float* W1 = (const float*)d_in[2];
    const float* b1 = (const float*)d_in[3];
    const float* W2 = (const float*)d_in[4];
    const float* b2 = (const float*)d_in[5];
    float* out = (float*)d_out;

    const int* src = ei;              // edge_index[0]
    const int* dst = ei + N_EDGES;    // edge_index[1]

    // workspace layout (bytes), 16B-aligned. TOTAL = 58,000,000 B (55.3 MiB)
    // (round-0 layout used 115.6 MB and corrupted adjacent harness buffers)
    char* ws = (char*)d_ws;
    float* xa  = (float*)(ws + 0);            // 100000*128*4 = 51,200,000
    float* h2  = (float*)(ws + 51200000);     //  6,400,000
    float* dis = (float*)(ws + 57600000);     //    400,000  (deg -> rsqrt in place)

    deg_init_kernel <<<(N_NODES + 255) / 256, 256, 0, stream>>>(dis);
    deg_count_kernel<<<(N_EDGES + 255) / 256, 256, 0, stream>>>(dst, dis);
    dis_kernel      <<<(N_NODES + 255) / 256, 256, 0, stream>>>(dis);

    xa_init_kernel  <<<N_NODES * 128 / 4 / 256, 256, 0, stream>>>(x, dis, xa);
    scatter_x_kernel<<<N_EDGES * 128 / 256, 256, 0, stream>>>(src, dst, dis, x, xa);

    gemm1_kernel    <<<N_NODES / 32, 256, 0, stream>>>(xa, W1, b1);
    gemm2_kernel    <<<N_NODES / 16, 256, 0, stream>>>(xa, W2, dis, h2, out);
    scatter2_kernel <<<N_EDGES * 16 / 256, 256, 0, stream>>>(src, dst, dis, h2, out);

    lsm_kernel      <<<(N_NODES + 255) / 256, 256, 0, stream>>>(b2, out);
}

// Round 3
// 634.602 us; speedup vs baseline: 1.7098x; 1.7098x over previous
//
#include <hip/hip_runtime.h>
#include <math.h>

#define N_NODES 100000
#define N_EDGES 1600000
#define NBLK 391   // ceil(100000/256)

// ---------------- CSR build: histogram -> scan -> place ----------------

__global__ __launch_bounds__(256) void zero_cnt_kernel(int* __restrict__ cnt) {
    int i = blockIdx.x * 256 + threadIdx.x;
    if (i < N_NODES) cnt[i] = 0;
}

__global__ __launch_bounds__(256) void deg_count_kernel(const int* __restrict__ dst,
                                                        int* __restrict__ cnt) {
    int e = blockIdx.x * 256 + threadIdx.x;
    if (e < N_EDGES) atomicAdd(&cnt[dst[e]], 1);
}

// dis[i] = rsqrt(in_degree + 1 self loop). Must run BEFORE scan destroys cnt.
__global__ __launch_bounds__(256) void dis_kernel(const int* __restrict__ cnt,
                                                  float* __restrict__ dis) {
    int i = blockIdx.x * 256 + threadIdx.x;
    if (i < N_NODES) dis[i] = rsqrtf((float)cnt[i] + 1.0f);
}

// Per-block exclusive scan (in place) + block totals.
__global__ __launch_bounds__(256) void scan_blk_kernel(int* __restrict__ cnt,
                                                       int* __restrict__ blk) {
    __shared__ int s[256];
    int t = threadIdx.x, i = blockIdx.x * 256 + t;
    int v = (i < N_NODES) ? cnt[i] : 0;
    s[t] = v;
    __syncthreads();
    for (int off = 1; off < 256; off <<= 1) {
        int u = (t >= off) ? s[t - off] : 0;
        __syncthreads();
        s[t] += u;
        __syncthreads();
    }
    if (i < N_NODES) cnt[i] = s[t] - v;          // exclusive within block
    if (t == 255) blk[blockIdx.x] = s[255];      // block total
}

// Exclusive scan of the 391 block totals (single block of 512).
__global__ __launch_bounds__(512) void scan_top_kernel(int* __restrict__ blk) {
    __shared__ int s[512];
    int t = threadIdx.x;
    int v = (t < NBLK) ? blk[t] : 0;
    s[t] = v;
    __syncthreads();
    for (int off = 1; off < 512; off <<= 1) {
        int u = (t >= off) ? s[t - off] : 0;
        __syncthreads();
        s[t] += u;
        __syncthreads();
    }
    if (t < NBLK) blk[t] = s[t] - v;
}

__global__ __launch_bounds__(256) void scan_add_kernel(int* __restrict__ cnt,
                                                       const int* __restrict__ blk) {
    int i = blockIdx.x * 256 + threadIdx.x;
    if (i < N_NODES) cnt[i] += blk[blockIdx.x];   // cnt[i] = start of node i
}

// col_idx[pos] = src, bucketed by dst. Afterwards cnt[i] = end ptr of node i.
__global__ __launch_bounds__(256) void place_kernel(const int* __restrict__ src,
                                                    const int* __restrict__ dst,
                                                    int* __restrict__ cnt,
                                                    int* __restrict__ col) {
    int e = blockIdx.x * 256 + threadIdx.x;
    if (e < N_EDGES) {
        int p = atomicAdd(&cnt[dst[e]], 1);
        col[p] = src[e];
    }
}

// ---------------- layer-1 aggregation (gather, no atomics) ----------------
// One wave per node, float2 per lane. xa[n] = dis_n*( x[n]*dis_n + sum x[s]*dis_s ).

__global__ __launch_bounds__(256) void gather1_kernel(const int* __restrict__ col,
                                                      const int* __restrict__ cnt,
                                                      const float* __restrict__ dis,
                                                      const float* __restrict__ x,
                                                      float* __restrict__ xa) {
    int t = threadIdx.x;
    int node = blockIdx.x * 4 + (t >> 6);        // 25000 blocks * 4 = 100000 exact
    int lane = t & 63;
    float dn = dis[node];
    int beg = (node == 0) ? 0 : cnt[node - 1];   // cnt holds end-pointers after place
    int end = cnt[node];
    const float2* xr = (const float2*)x;
    float2 self = xr[node * 64 + lane];
    float2 acc = make_float2(self.x * dn, self.y * dn);
    for (int k = beg; k < end; ++k) {
        int s = col[k];
        float w = dis[s];
        float2 v = xr[s * 64 + lane];
        acc.x += v.x * w;
        acc.y += v.y * w;
    }
    ((float2*)xa)[node * 64 + lane] = make_float2(acc.x * dn, acc.y * dn);
}

// ---------------- GEMM1 (in-place): xa = relu(xa @ W1 + b1) ----------------

__global__ __launch_bounds__(256) void gemm1_kernel(float* __restrict__ xa,
                                                    const float* __restrict__ W,
                                                    const float* __restrict__ b1) {
    __shared__ float As[32][32];
    __shared__ float Bs[32][128];
    const int t = threadIdx.x;
    const int m0 = blockIdx.x * 32;
    const int tc = t & 31;
    const int tr = t >> 5;
    float acc[4][4] = {};

    for (int kb = 0; kb < 128; kb += 32) {
        {
            int row = t >> 3, col = (t & 7) << 2;
            *(float4*)&As[row][col] = *(const float4*)&xa[(m0 + row) * 128 + kb + col];
        }
        #pragma unroll
        for (int i = 0; i < 4; i++) {
            int p = t + i * 256;
            int row = p >> 5, col = (p & 31) << 2;
            *(float4*)&Bs[row][col] = *(const float4*)&W[(kb + row) * 128 + col];
        }
        __syncthreads();
        #pragma unroll
        for (int k = 0; k < 32; k += 4) {
            float4 av[4], bv[4];
            #pragma unroll
            for (int i = 0; i < 4; i++) av[i] = *(const float4*)&As[tr * 4 + i][k];
            #pragma unroll
            for (int j = 0; j < 4; j++) bv[j] = *(const float4*)&Bs[k + j][tc * 4];
            #pragma unroll
            for (int i = 0; i < 4; i++) {
                acc[i][0] += av[i].x * bv[0].x + av[i].y * bv[1].x + av[i].z * bv[2].x + av[i].w * bv[3].x;
                acc[i][1] += av[i].x * bv[0].y + av[i].y * bv[1].y + av[i].z * bv[2].y + av[i].w * bv[3].y;
                acc[i][2] += av[i].x * bv[0].z + av[i].y * bv[1].z + av[i].z * bv[2].z + av[i].w * bv[3].z;
                acc[i][3] += av[i].x * bv[0].w + av[i].y * bv[1].w + av[i].z * bv[2].w + av[i].w * bv[3].w;
            }
        }
        __syncthreads();
    }
    float4 bb = *(const float4*)&b1[tc * 4];
    #pragma unroll
    for (int i = 0; i < 4; i++) {
        int m = m0 + tr * 4 + i;
        *(float4*)&xa[m * 128 + tc * 4] = make_float4(fmaxf(acc[i][0] + bb.x, 0.0f),
                                                      fmaxf(acc[i][1] + bb.y, 0.0f),
                                                      fmaxf(acc[i][2] + bb.z, 0.0f),
                                                      fmaxf(acc[i][3] + bb.w, 0.0f));
    }
}

// ---------------- GEMM2 (in-place): h2 = xa @ W2 stored into first 16 cols of xa ----------------
// Block reads ONLY its own 16 rows into LDS, then writes only those rows -> no hazard.

__global__ __launch_bounds__(256) void gemm2_kernel(float* __restrict__ xa,
                                                    const float* __restrict__ W2) {
    __shared__ float As[16][132];
    __shared__ float Ws[128][16];
    const int t = threadIdx.x;
    const int m0 = blockIdx.x * 16;

    #pragma unroll
    for (int i = 0; i < 2; i++) {
        int p = t + i * 256;
        int row = p >> 2, col = (p & 3) << 2;
        *(float4*)&Ws[row][col] = *(const float4*)&W2[row * 16 + col];
    }
    #pragma unroll
    for (int i = 0; i < 2; i++) {
        int p = t + i * 256;
        int row = p >> 5, col = (p & 31) << 2;
        *(float4*)&As[row][col] = *(const float4*)&xa[(m0 + row) * 128 + col];
    }
    __syncthreads();

    const int ml = t >> 4, n = t & 15;
    float acc = 0.0f;
    #pragma unroll
    for (int k = 0; k < 128; k += 4) {
        float4 a = *(const float4*)&As[ml][k];
        acc += a.x * Ws[k][n] + a.y * Ws[k + 1][n] + a.z * Ws[k + 2][n] + a.w * Ws[k + 3][n];
    }
    xa[(m0 + ml) * 128 + n] = acc;   // h2 row lives at stride 128
}

// ---------------- layer-2 gather + bias + log-softmax (fused) ----------------
// 16 threads per node; shfl_xor butterflies over the 16-class dim.

__global__ __launch_bounds__(256) void gather2_lsm_kernel(const int* __restrict__ col,
                                                          const int* __restrict__ cnt,
                                                          const float* __restrict__ dis,
                                                          const float* __restrict__ xa,
                                                          const float* __restrict__ b2,
                                                          float* __restrict__ out) {
    int t = threadIdx.x;
    int node = blockIdx.x * 16 + (t >> 4);       // 6250 * 16 = 100000 exact
    int n = t & 15;
    float dn = dis[node];
    int beg = (node == 0) ? 0 : cnt[node - 1];
    int end = cnt[node];
    float acc = xa[node * 128 + n] * dn;         // self-loop term (h2 in-row)
    for (int k = beg; k < end; ++k) {
        int s = col[k];
        acc += xa[s * 128 + n] * dis[s];
    }
    float v = acc * dn + b2[n];
    float m = v;
    #pragma unroll
    for (int off = 1; off < 16; off <<= 1) m = fmaxf(m, __shfl_xor(m, off, 16));
    float ssum = expf(v - m);
    #pragma unroll
    for (int off = 1; off < 16; off <<= 1) ssum += __shfl_xor(ssum, off, 16);
    out[node * 16 + n] = v - (m + logf(ssum));
}

// ---------------- launch ----------------

extern "C" void kernel_launch(void* const* d_in, const int* in_sizes, int n_in,
                              void* d_out, int out_size, void* d_ws, size_t ws_size,
                              hipStream_t stream) {
    const float* x  = (const float*)d_in[0];
    const int*   ei = (const int*)d_in[1];
    const float* W1 = (const float*)d_in[2];
    const float* b1 = (const float*)d_in[3];
    const float* W2 = (const float*)d_in[4];
    const float* b2 = (const float*)d_in[5];
    float* out = (float*)d_out;

    const int* src = ei;              // edge_index[0]
    const int* dst = ei + N_EDGES;    // edge_index[1]

    // workspace layout (bytes). TOTAL = 58,401,564 (58.4 MB; 58.0 MB passed in R2)
    char* ws = (char*)d_ws;
    float* xa  = (float*)(ws + 0);            // 51,200,000  (agg-x -> h1 -> +h2 in-row)
    int*   col = (int*)  (ws + 51200000);     //  6,400,000  CSR column (src) indices
    float* dis = (float*)(ws + 57600000);     //    400,000
    int*   cnt = (int*)  (ws + 58000000);     //    400,000  histogram -> start -> end ptrs
    int*   blk = (int*)  (ws + 58400000);     //      1,564  scan partials

    zero_cnt_kernel  <<<NBLK, 256, 0, stream>>>(cnt);
    deg_count_kernel <<<N_EDGES / 256, 256, 0, stream>>>(dst, cnt);
    dis_kernel       <<<NBLK, 256, 0, stream>>>(cnt, dis);
    scan_blk_kernel  <<<NBLK, 256, 0, stream>>>(cnt, blk);
    scan_top_kernel  <<<1, 512, 0, stream>>>(blk);
    scan_add_kernel  <<<NBLK, 256, 0, stream>>>(cnt, blk);
    place_kernel     <<<N_EDGES / 256, 256, 0, stream>>>(src, dst, cnt, col);

    gather1_kernel   <<<N_NODES / 4, 256, 0, stream>>>(col, cnt, dis, x, xa);
    gemm1_kernel     <<<N_NODES / 32, 256, 0, stream>>>(xa, W1, b1);
    gemm2_kernel     <<<N_NODES / 16, 256, 0, stream>>>(xa, W2);
    gather2_lsm_kernel<<<N_NODES / 16, 256, 0, stream>>>(col, cnt, dis, xa, b2, out);
}

// Round 4
// 564.297 us; speedup vs baseline: 1.9228x; 1.1246x over previous
//
#include <hip/hip_runtime.h>
#include <math.h>

#define N_NODES 100000
#define N_EDGES 1600000
#define NBLK 391   // ceil(100000/256)

// ---------------- CSR build: histogram -> scan -> place ----------------

__global__ __launch_bounds__(256) void zero_cnt_kernel(int* __restrict__ cnt) {
    int i = blockIdx.x * 256 + threadIdx.x;
    if (i < N_NODES) cnt[i] = 0;
}

__global__ __launch_bounds__(256) void deg_count_kernel(const int* __restrict__ dst,
                                                        int* __restrict__ cnt) {
    int e = blockIdx.x * 256 + threadIdx.x;
    if (e < N_EDGES) atomicAdd(&cnt[dst[e]], 1);
}

// dis[i] = rsqrt(in_degree + 1 self loop). Must run BEFORE scan destroys cnt.
__global__ __launch_bounds__(256) void dis_kernel(const int* __restrict__ cnt,
                                                  float* __restrict__ dis) {
    int i = blockIdx.x * 256 + threadIdx.x;
    if (i < N_NODES) dis[i] = rsqrtf((float)cnt[i] + 1.0f);
}

// Per-block exclusive scan (in place) + block totals.
__global__ __launch_bounds__(256) void scan_blk_kernel(int* __restrict__ cnt,
                                                       int* __restrict__ blk) {
    __shared__ int s[256];
    int t = threadIdx.x, i = blockIdx.x * 256 + t;
    int v = (i < N_NODES) ? cnt[i] : 0;
    s[t] = v;
    __syncthreads();
    for (int off = 1; off < 256; off <<= 1) {
        int u = (t >= off) ? s[t - off] : 0;
        __syncthreads();
        s[t] += u;
        __syncthreads();
    }
    if (i < N_NODES) cnt[i] = s[t] - v;
    if (t == 255) blk[blockIdx.x] = s[255];
}

__global__ __launch_bounds__(512) void scan_top_kernel(int* __restrict__ blk) {
    __shared__ int s[512];
    int t = threadIdx.x;
    int v = (t < NBLK) ? blk[t] : 0;
    s[t] = v;
    __syncthreads();
    for (int off = 1; off < 512; off <<= 1) {
        int u = (t >= off) ? s[t - off] : 0;
        __syncthreads();
        s[t] += u;
        __syncthreads();
    }
    if (t < NBLK) blk[t] = s[t] - v;
}

__global__ __launch_bounds__(256) void scan_add_kernel(int* __restrict__ cnt,
                                                       const int* __restrict__ blk) {
    int i = blockIdx.x * 256 + threadIdx.x;
    if (i < N_NODES) cnt[i] += blk[blockIdx.x];
}

// col[pos] = src, bucketed by dst. Afterwards cnt[i] = end ptr of node i.
__global__ __launch_bounds__(256) void place_kernel(const int* __restrict__ src,
                                                    const int* __restrict__ dst,
                                                    int* __restrict__ cnt,
                                                    int* __restrict__ col) {
    int e = blockIdx.x * 256 + threadIdx.x;
    if (e < N_EDGES) {
        int p = atomicAdd(&cnt[dst[e]], 1);
        col[p] = src[e];
    }
}

// ---------------- layer-1 aggregation (gather, 4-deep MLP unroll) ----------------
// One wave per node, float2 per lane; 4 independent edge-rows in flight.

__global__ __launch_bounds__(256) void gather1_kernel(const int* __restrict__ col,
                                                      const int* __restrict__ cnt,
                                                      const float* __restrict__ dis,
                                                      const float* __restrict__ x,
                                                      float* __restrict__ xa) {
    int t = threadIdx.x;
    int node = blockIdx.x * 4 + (t >> 6);        // 25000 blocks * 4 = 100000 exact
    int lane = t & 63;
    float dn = dis[node];
    int beg = (node == 0) ? 0 : cnt[node - 1];   // cnt = end-pointers after place
    int end = cnt[node];
    const float2* xr = (const float2*)x;
    float2 self = xr[node * 64 + lane];
    float2 a0 = make_float2(self.x * dn, self.y * dn);
    float2 a1 = make_float2(0.f, 0.f);
    float2 a2 = make_float2(0.f, 0.f);
    float2 a3 = make_float2(0.f, 0.f);
    int k = beg;
    for (; k + 4 <= end; k += 4) {
        int s0 = col[k], s1 = col[k + 1], s2 = col[k + 2], s3 = col[k + 3];
        float w0 = dis[s0], w1 = dis[s1], w2 = dis[s2], w3 = dis[s3];
        float2 v0 = xr[s0 * 64 + lane];
        float2 v1 = xr[s1 * 64 + lane];
        float2 v2 = xr[s2 * 64 + lane];
        float2 v3 = xr[s3 * 64 + lane];
        a0.x += v0.x * w0; a0.y += v0.y * w0;
        a1.x += v1.x * w1; a1.y += v1.y * w1;
        a2.x += v2.x * w2; a2.y += v2.y * w2;
        a3.x += v3.x * w3; a3.y += v3.y * w3;
    }
    for (; k < end; ++k) {
        int s = col[k];
        float w = dis[s];
        float2 v = xr[s * 64 + lane];
        a0.x += v.x * w; a0.y += v.y * w;
    }
    float rx = (a0.x + a1.x) + (a2.x + a3.x);
    float ry = (a0.y + a1.y) + (a2.y + a3.y);
    ((float2*)xa)[node * 64 + lane] = make_float2(rx * dn, ry * dn);
}

// ---------------- GEMM1 (in-place): xa = relu(xa @ W1 + b1) ----------------

__global__ __launch_bounds__(256) void gemm1_kernel(float* __restrict__ xa,
                                                    const float* __restrict__ W,
                                                    const float* __restrict__ b1) {
    __shared__ float As[32][32];
    __shared__ float Bs[32][128];
    const int t = threadIdx.x;
    const int m0 = blockIdx.x * 32;
    const int tc = t & 31;
    const int tr = t >> 5;
    float acc[4][4] = {};

    for (int kb = 0; kb < 128; kb += 32) {
        {
            int row = t >> 3, col = (t & 7) << 2;
            *(float4*)&As[row][col] = *(const float4*)&xa[(m0 + row) * 128 + kb + col];
        }
        #pragma unroll
        for (int i = 0; i < 4; i++) {
            int p = t + i * 256;
            int row = p >> 5, col = (p & 31) << 2;
            *(float4*)&Bs[row][col] = *(const float4*)&W[(kb + row) * 128 + col];
        }
        __syncthreads();
        #pragma unroll
        for (int k = 0; k < 32; k += 4) {
            float4 av[4], bv[4];
            #pragma unroll
            for (int i = 0; i < 4; i++) av[i] = *(const float4*)&As[tr * 4 + i][k];
            #pragma unroll
            for (int j = 0; j < 4; j++) bv[j] = *(const float4*)&Bs[k + j][tc * 4];
            #pragma unroll
            for (int i = 0; i < 4; i++) {
                acc[i][0] += av[i].x * bv[0].x + av[i].y * bv[1].x + av[i].z * bv[2].x + av[i].w * bv[3].x;
                acc[i][1] += av[i].x * bv[0].y + av[i].y * bv[1].y + av[i].z * bv[2].y + av[i].w * bv[3].y;
                acc[i][2] += av[i].x * bv[0].z + av[i].y * bv[1].z + av[i].z * bv[2].z + av[i].w * bv[3].z;
                acc[i][3] += av[i].x * bv[0].w + av[i].y * bv[1].w + av[i].z * bv[2].w + av[i].w * bv[3].w;
            }
        }
        __syncthreads();
    }
    float4 bb = *(const float4*)&b1[tc * 4];
    #pragma unroll
    for (int i = 0; i < 4; i++) {
        int m = m0 + tr * 4 + i;
        *(float4*)&xa[m * 128 + tc * 4] = make_float4(fmaxf(acc[i][0] + bb.x, 0.0f),
                                                      fmaxf(acc[i][1] + bb.y, 0.0f),
                                                      fmaxf(acc[i][2] + bb.z, 0.0f),
                                                      fmaxf(acc[i][3] + bb.w, 0.0f));
    }
}

// ---------------- GEMM2 (in-place): h2 = xa @ W2 into first 16 cols of own rows ----------------

__global__ __launch_bounds__(256) void gemm2_kernel(float* __restrict__ xa,
                                                    const float* __restrict__ W2) {
    __shared__ float As[16][132];
    __shared__ float Ws[128][16];
    const int t = threadIdx.x;
    const int m0 = blockIdx.x * 16;

    #pragma unroll
    for (int i = 0; i < 2; i++) {
        int p = t + i * 256;
        int row = p >> 2, col = (p & 3) << 2;
        *(float4*)&Ws[row][col] = *(const float4*)&W2[row * 16 + col];
    }
    #pragma unroll
    for (int i = 0; i < 2; i++) {
        int p = t + i * 256;
        int row = p >> 5, col = (p & 31) << 2;
        *(float4*)&As[row][col] = *(const float4*)&xa[(m0 + row) * 128 + col];
    }
    __syncthreads();

    const int ml = t >> 4, n = t & 15;
    float acc = 0.0f;
    #pragma unroll
    for (int k = 0; k < 128; k += 4) {
        float4 a = *(const float4*)&As[ml][k];
        acc += a.x * Ws[k][n] + a.y * Ws[k + 1][n] + a.z * Ws[k + 2][n] + a.w * Ws[k + 3][n];
    }
    xa[(m0 + ml) * 128 + n] = acc;
}

// ---------------- layer-2 gather + bias + log-softmax (fused, 4-deep unroll) ----------------

__global__ __launch_bounds__(256) void gather2_lsm_kernel(const int* __restrict__ col,
                                                          const int* __restrict__ cnt,
                                                          const float* __restrict__ dis,
                                                          const float* __restrict__ xa,
                                                          const float* __restrict__ b2,
                                                          float* __restrict__ out) {
    int t = threadIdx.x;
    int node = blockIdx.x * 16 + (t >> 4);       // 6250 * 16 = 100000 exact
    int n = t & 15;
    float dn = dis[node];
    int beg = (node == 0) ? 0 : cnt[node - 1];
    int end = cnt[node];
    float a0 = xa[node * 128 + n] * dn;          // self-loop term (h2 in-row)
    float a1 = 0.f, a2 = 0.f, a3 = 0.f;
    int k = beg;
    for (; k + 4 <= end; k += 4) {
        int s0 = col[k], s1 = col[k + 1], s2 = col[k + 2], s3 = col[k + 3];
        float w0 = dis[s0], w1 = dis[s1], w2 = dis[s2], w3 = dis[s3];
        a0 += xa[s0 * 128 + n] * w0;
        a1 += xa[s1 * 128 + n] * w1;
        a2 += xa[s2 * 128 + n] * w2;
        a3 += xa[s3 * 128 + n] * w3;
    }
    for (; k < end; ++k) {
        int s = col[k];
        a0 += xa[s * 128 + n] * dis[s];
    }
    float acc = (a0 + a1) + (a2 + a3);
    float v = acc * dn + b2[n];
    float m = v;
    #pragma unroll
    for (int off = 1; off < 16; off <<= 1) m = fmaxf(m, __shfl_xor(m, off, 16));
    float ssum = expf(v - m);
    #pragma unroll
    for (int off = 1; off < 16; off <<= 1) ssum += __shfl_xor(ssum, off, 16);
    out[node * 16 + n] = v - (m + logf(ssum));
}

// ---------------- launch ----------------

extern "C" void kernel_launch(void* const* d_in, const int* in_sizes, int n_in,
                              void* d_out, int out_size, void* d_ws, size_t ws_size,
                              hipStream_t stream) {
    const float* x  = (const float*)d_in[0];
    const int*   ei = (const int*)d_in[1];
    const float* W1 = (const float*)d_in[2];
    const float* b1 = (const float*)d_in[3];
    const float* W2 = (const float*)d_in[4];
    const float* b2 = (const float*)d_in[5];
    float* out = (float*)d_out;

    const int* src = ei;              // edge_index[0]
    const int* dst = ei + N_EDGES;    // edge_index[1]

    // workspace layout (bytes). TOTAL = 58,401,564 B (58.4 MB passed in R2/R3)
    char* ws = (char*)d_ws;
    float* xa  = (float*)(ws + 0);            // 51,200,000  (agg-x -> h1 -> +h2 in-row)
    int*   col = (int*)  (ws + 51200000);     //  6,400,000  CSR column (src) indices
    float* dis = (float*)(ws + 57600000);     //    400,000
    int*   cnt = (int*)  (ws + 58000000);     //    400,000  histogram -> start -> end ptrs
    int*   blk = (int*)  (ws + 58400000);     //      1,564  scan partials

    zero_cnt_kernel  <<<NBLK, 256, 0, stream>>>(cnt);
    deg_count_kernel <<<N_EDGES / 256, 256, 0, stream>>>(dst, cnt);
    dis_kernel       <<<NBLK, 256, 0, stream>>>(cnt, dis);
    scan_blk_kernel  <<<NBLK, 256, 0, stream>>>(cnt, blk);
    scan_top_kernel  <<<1, 512, 0, stream>>>(blk);
    scan_add_kernel  <<<NBLK, 256, 0, stream>>>(cnt, blk);
    place_kernel     <<<N_EDGES / 256, 256, 0, stream>>>(src, dst, cnt, col);

    gather1_kernel   <<<N_NODES / 4, 256, 0, stream>>>(col, cnt, dis, x, xa);
    gemm1_kernel     <<<N_NODES / 32, 256, 0, stream>>>(xa, W1, b1);
    gemm2_kernel     <<<N_NODES / 16, 256, 0, stream>>>(xa, W2);
    gather2_lsm_kernel<<<N_NODES / 16, 256, 0, stream>>>(col, cnt, dis, xa, b2, out);
}

// Round 5
// 469.302 us; speedup vs baseline: 2.3120x; 1.2024x over previous
//
#include <hip/hip_runtime.h>
#include <math.h>

#define N_NODES 100000
#define N_EDGES 1600000
#define NBLK 391   // ceil(100000/256)

// ---------------- CSR build: histogram(+rank) -> scan -> atomic-free place ----------------

__global__ __launch_bounds__(256) void zero_cnt_kernel(int* __restrict__ cnt) {
    int i = blockIdx.x * 256 + threadIdx.x;
    if (i < N_NODES) cnt[i] = 0;
}

// Count in-degree AND capture each edge's rank within its dst bucket.
// enc[e] = src | (rank<<17): src < 2^17 (100000), rank < 2^15 (max in-deg ~45, Poisson(16)).
__global__ __launch_bounds__(256) void deg_count_rank_kernel(const int* __restrict__ src,
                                                             const int* __restrict__ dst,
                                                             int* __restrict__ cnt,
                                                             int* __restrict__ enc) {
    int e = blockIdx.x * 256 + threadIdx.x;
    if (e < N_EDGES) {
        int r = atomicAdd(&cnt[dst[e]], 1);
        enc[e] = src[e] | (r << 17);
    }
}

// dis[i] = rsqrt(in_degree + 1 self loop). Runs BEFORE scan destroys counts.
__global__ __launch_bounds__(256) void dis_kernel(const int* __restrict__ cnt,
                                                  float* __restrict__ dis) {
    int i = blockIdx.x * 256 + threadIdx.x;
    if (i < N_NODES) dis[i] = rsqrtf((float)cnt[i] + 1.0f);
}

// Per-block exclusive scan (in place) + block totals.
__global__ __launch_bounds__(256) void scan_blk_kernel(int* __restrict__ cnt,
                                                       int* __restrict__ blk) {
    __shared__ int s[256];
    int t = threadIdx.x, i = blockIdx.x * 256 + t;
    int v = (i < N_NODES) ? cnt[i] : 0;
    s[t] = v;
    __syncthreads();
    for (int off = 1; off < 256; off <<= 1) {
        int u = (t >= off) ? s[t - off] : 0;
        __syncthreads();
        s[t] += u;
        __syncthreads();
    }
    if (i < N_NODES) cnt[i] = s[t] - v;
    if (t == 255) blk[blockIdx.x] = s[255];
}

__global__ __launch_bounds__(512) void scan_top_kernel(int* __restrict__ blk) {
    __shared__ int s[512];
    int t = threadIdx.x;
    int v = (t < NBLK) ? blk[t] : 0;
    s[t] = v;
    __syncthreads();
    for (int off = 1; off < 512; off <<= 1) {
        int u = (t >= off) ? s[t - off] : 0;
        __syncthreads();
        s[t] += u;
        __syncthreads();
    }
    if (t < NBLK) blk[t] = s[t] - v;
}

__global__ __launch_bounds__(256) void scan_add_kernel(int* __restrict__ cnt,
                                                       const int* __restrict__ blk) {
    int i = blockIdx.x * 256 + threadIdx.x;
    if (i < N_NODES) cnt[i] += blk[blockIdx.x];   // cnt[i] = start of node i (stays!)
}

// Atomic-free placement: position = start[dst] + rank. All loads coalesced/L2;
// store is fire-and-forget (no RMW-return dependency).
__global__ __launch_bounds__(256) void place_kernel(const int* __restrict__ dst,
                                                    const int* __restrict__ enc,
                                                    const int* __restrict__ start,
                                                    int* __restrict__ col) {
    int e = blockIdx.x * 256 + threadIdx.x;
    int d = dst[e];
    int v = enc[e];
    col[start[d] + (v >> 17)] = v & 0x1FFFF;
}

// ---------------- layer-1 aggregation (gather, 8-deep MLP unroll) ----------------
// One wave per node, float2 per lane; 8 independent edge-rows in flight.

__global__ __launch_bounds__(256) void gather1_kernel(const int* __restrict__ col,
                                                      const int* __restrict__ cnt,
                                                      const float* __restrict__ dis,
                                                      const float* __restrict__ x,
                                                      float* __restrict__ xa) {
    int t = threadIdx.x;
    int node = blockIdx.x * 4 + (t >> 6);        // 25000 blocks * 4 = 100000 exact
    int lane = t & 63;
    float dn = dis[node];
    int beg = cnt[node];                          // cnt = start offsets
    int end = (node == N_NODES - 1) ? N_EDGES : cnt[node + 1];
    const float2* xr = (const float2*)x;
    float2 self = xr[node * 64 + lane];
    float2 a0 = make_float2(self.x * dn, self.y * dn);
    float2 a1 = make_float2(0.f, 0.f), a2 = make_float2(0.f, 0.f), a3 = make_float2(0.f, 0.f);
    float2 a4 = make_float2(0.f, 0.f), a5 = make_float2(0.f, 0.f);
    float2 a6 = make_float2(0.f, 0.f), a7 = make_float2(0.f, 0.f);
    int k = beg;
    for (; k + 8 <= end; k += 8) {
        int s0 = col[k], s1 = col[k + 1], s2 = col[k + 2], s3 = col[k + 3];
        int s4 = col[k + 4], s5 = col[k + 5], s6 = col[k + 6], s7 = col[k + 7];
        float w0 = dis[s0], w1 = dis[s1], w2 = dis[s2], w3 = dis[s3];
        float w4 = dis[s4], w5 = dis[s5], w6 = dis[s6], w7 = dis[s7];
        float2 v0 = xr[s0 * 64 + lane], v1 = xr[s1 * 64 + lane];
        float2 v2 = xr[s2 * 64 + lane], v3 = xr[s3 * 64 + lane];
        float2 v4 = xr[s4 * 64 + lane], v5 = xr[s5 * 64 + lane];
        float2 v6 = xr[s6 * 64 + lane], v7 = xr[s7 * 64 + lane];
        a0.x += v0.x * w0; a0.y += v0.y * w0;
        a1.x += v1.x * w1; a1.y += v1.y * w1;
        a2.x += v2.x * w2; a2.y += v2.y * w2;
        a3.x += v3.x * w3; a3.y += v3.y * w3;
        a4.x += v4.x * w4; a4.y += v4.y * w4;
        a5.x += v5.x * w5; a5.y += v5.y * w5;
        a6.x += v6.x * w6; a6.y += v6.y * w6;
        a7.x += v7.x * w7; a7.y += v7.y * w7;
    }
    for (; k + 4 <= end; k += 4) {
        int s0 = col[k], s1 = col[k + 1], s2 = col[k + 2], s3 = col[k + 3];
        float w0 = dis[s0], w1 = dis[s1], w2 = dis[s2], w3 = dis[s3];
        float2 v0 = xr[s0 * 64 + lane], v1 = xr[s1 * 64 + lane];
        float2 v2 = xr[s2 * 64 + lane], v3 = xr[s3 * 64 + lane];
        a0.x += v0.x * w0; a0.y += v0.y * w0;
        a1.x += v1.x * w1; a1.y += v1.y * w1;
        a2.x += v2.x * w2; a2.y += v2.y * w2;
        a3.x += v3.x * w3; a3.y += v3.y * w3;
    }
    for (; k < end; ++k) {
        int s = col[k];
        float w = dis[s];
        float2 v = xr[s * 64 + lane];
        a0.x += v.x * w; a0.y += v.y * w;
    }
    float rx = ((a0.x + a1.x) + (a2.x + a3.x)) + ((a4.x + a5.x) + (a6.x + a7.x));
    float ry = ((a0.y + a1.y) + (a2.y + a3.y)) + ((a4.y + a5.y) + (a6.y + a7.y));
    ((float2*)xa)[node * 64 + lane] = make_float2(rx * dn, ry * dn);
}

// ---------------- GEMM1 (in-place): xa = relu(xa @ W1 + b1) ----------------

__global__ __launch_bounds__(256) void gemm1_kernel(float* __restrict__ xa,
                                                    const float* __restrict__ W,
                                                    const float* __restrict__ b1) {
    __shared__ float As[32][32];
    __shared__ float Bs[32][128];
    const int t = threadIdx.x;
    const int m0 = blockIdx.x * 32;
    const int tc = t & 31;
    const int tr = t >> 5;
    float acc[4][4] = {};

    for (int kb = 0; kb < 128; kb += 32) {
        {
            int row = t >> 3, col = (t & 7) << 2;
            *(float4*)&As[row][col] = *(const float4*)&xa[(m0 + row) * 128 + kb + col];
        }
        #pragma unroll
        for (int i = 0; i < 4; i++) {
            int p = t + i * 256;
            int row = p >> 5, col = (p & 31) << 2;
            *(float4*)&Bs[row][col] = *(const float4*)&W[(kb + row) * 128 + col];
        }
        __syncthreads();
        #pragma unroll
        for (int k = 0; k < 32; k += 4) {
            float4 av[4], bv[4];
            #pragma unroll
            for (int i = 0; i < 4; i++) av[i] = *(const float4*)&As[tr * 4 + i][k];
            #pragma unroll
            for (int j = 0; j < 4; j++) bv[j] = *(const float4*)&Bs[k + j][tc * 4];
            #pragma unroll
            for (int i = 0; i < 4; i++) {
                acc[i][0] += av[i].x * bv[0].x + av[i].y * bv[1].x + av[i].z * bv[2].x + av[i].w * bv[3].x;
                acc[i][1] += av[i].x * bv[0].y + av[i].y * bv[1].y + av[i].z * bv[2].y + av[i].w * bv[3].y;
                acc[i][2] += av[i].x * bv[0].z + av[i].y * bv[1].z + av[i].z * bv[2].z + av[i].w * bv[3].z;
                acc[i][3] += av[i].x * bv[0].w + av[i].y * bv[1].w + av[i].z * bv[2].w + av[i].w * bv[3].w;
            }
        }
        __syncthreads();
    }
    float4 bb = *(const float4*)&b1[tc * 4];
    #pragma unroll
    for (int i = 0; i < 4; i++) {
        int m = m0 + tr * 4 + i;
        *(float4*)&xa[m * 128 + tc * 4] = make_float4(fmaxf(acc[i][0] + bb.x, 0.0f),
                                                      fmaxf(acc[i][1] + bb.y, 0.0f),
                                                      fmaxf(acc[i][2] + bb.z, 0.0f),
                                                      fmaxf(acc[i][3] + bb.w, 0.0f));
    }
}

// ---------------- GEMM2 (in-place): h2 = xa @ W2 into first 16 cols of own rows ----------------

__global__ __launch_bounds__(256) void gemm2_kernel(float* __restrict__ xa,
                                                    const float* __restrict__ W2) {
    __shared__ float As[16][132];
    __shared__ float Ws[128][16];
    const int t = threadIdx.x;
    const int m0 = blockIdx.x * 16;

    #pragma unroll
    for (int i = 0; i < 2; i++) {
        int p = t + i * 256;
        int row = p >> 2, col = (p & 3) << 2;
        *(float4*)&Ws[row][col] = *(const float4*)&W2[row * 16 + col];
    }
    #pragma unroll
    for (int i = 0; i < 2; i++) {
        int p = t + i * 256;
        int row = p >> 5, col = (p & 31) << 2;
        *(float4*)&As[row][col] = *(const float4*)&xa[(m0 + row) * 128 + col];
    }
    __syncthreads();

    const int ml = t >> 4, n = t & 15;
    float acc = 0.0f;
    #pragma unroll
    for (int k = 0; k < 128; k += 4) {
        float4 a = *(const float4*)&As[ml][k];
        acc += a.x * Ws[k][n] + a.y * Ws[k + 1][n] + a.z * Ws[k + 2][n] + a.w * Ws[k + 3][n];
    }
    xa[(m0 + ml) * 128 + n] = acc;
}

// ---------------- layer-2 gather + bias + log-softmax (fused, 8-deep unroll) ----------------

__global__ __launch_bounds__(256) void gather2_lsm_kernel(const int* __restrict__ col,
                                                          const int* __restrict__ cnt,
                                                          const float* __restrict__ dis,
                                                          const float* __restrict__ xa,
                                                          const float* __restrict__ b2,
                                                          float* __restrict__ out) {
    int t = threadIdx.x;
    int node = blockIdx.x * 16 + (t >> 4);       // 6250 * 16 = 100000 exact
    int n = t & 15;
    float dn = dis[node];
    int beg = cnt[node];
    int end = (node == N_NODES - 1) ? N_EDGES : cnt[node + 1];
    float a0 = xa[node * 128 + n] * dn;          // self-loop term (h2 in-row)
    float a1 = 0.f, a2 = 0.f, a3 = 0.f, a4 = 0.f, a5 = 0.f, a6 = 0.f, a7 = 0.f;
    int k = beg;
    for (; k + 8 <= end; k += 8) {
        int s0 = col[k], s1 = col[k + 1], s2 = col[k + 2], s3 = col[k + 3];
        int s4 = col[k + 4], s5 = col[k + 5], s6 = col[k + 6], s7 = col[k + 7];
        a0 += xa[s0 * 128 + n] * dis[s0];
        a1 += xa[s1 * 128 + n] * dis[s1];
        a2 += xa[s2 * 128 + n] * dis[s2];
        a3 += xa[s3 * 128 + n] * dis[s3];
        a4 += xa[s4 * 128 + n] * dis[s4];
        a5 += xa[s5 * 128 + n] * dis[s5];
        a6 += xa[s6 * 128 + n] * dis[s6];
        a7 += xa[s7 * 128 + n] * dis[s7];
    }
    for (; k + 4 <= end; k += 4) {
        int s0 = col[k], s1 = col[k + 1], s2 = col[k + 2], s3 = col[k + 3];
        a0 += xa[s0 * 128 + n] * dis[s0];
        a1 += xa[s1 * 128 + n] * dis[s1];
        a2 += xa[s2 * 128 + n] * dis[s2];
        a3 += xa[s3 * 128 + n] * dis[s3];
    }
    for (; k < end; ++k) {
        int s = col[k];
        a0 += xa[s * 128 + n] * dis[s];
    }
    float acc = ((a0 + a1) + (a2 + a3)) + ((a4 + a5) + (a6 + a7));
    float v = acc * dn + b2[n];
    float m = v;
    #pragma unroll
    for (int off = 1; off < 16; off <<= 1) m = fmaxf(m, __shfl_xor(m, off, 16));
    float ssum = expf(v - m);
    #pragma unroll
    for (int off = 1; off < 16; off <<= 1) ssum += __shfl_xor(ssum, off, 16);
    out[node * 16 + n] = v - (m + logf(ssum));
}

// ---------------- launch ----------------

extern "C" void kernel_launch(void* const* d_in, const int* in_sizes, int n_in,
                              void* d_out, int out_size, void* d_ws, size_t ws_size,
                              hipStream_t stream) {
    const float* x  = (const float*)d_in[0];
    const int*   ei = (const int*)d_in[1];
    const float* W1 = (const float*)d_in[2];
    const float* b1 = (const float*)d_in[3];
    const float* W2 = (const float*)d_in[4];
    const float* b2 = (const float*)d_in[5];
    float* out = (float*)d_out;

    const int* src = ei;              // edge_index[0]
    const int* dst = ei + N_EDGES;    // edge_index[1]

    // workspace layout (bytes). TOTAL = 58,401,564 B (unchanged; proven safe).
    // enc aliases the first 6.4 MB of xa: dead until gather1 overwrites xa.
    char* ws = (char*)d_ws;
    float* xa  = (float*)(ws + 0);            // 51,200,000  (agg-x -> h1 -> +h2 in-row)
    int*   enc = (int*)  (ws + 0);            //  6,400,000  (src|rank<<17, CSR build only)
    int*   col = (int*)  (ws + 51200000);     //  6,400,000  CSR column (src) indices
    float* dis = (float*)(ws + 57600000);     //    400,000
    int*   cnt = (int*)  (ws + 58000000);     //    400,000  histogram -> start offsets
    int*   blk = (int*)  (ws + 58400000);     //      1,564  scan partials

    zero_cnt_kernel      <<<NBLK, 256, 0, stream>>>(cnt);
    deg_count_rank_kernel<<<N_EDGES / 256, 256, 0, stream>>>(src, dst, cnt, enc);
    dis_kernel           <<<NBLK, 256, 0, stream>>>(cnt, dis);
    scan_blk_kernel      <<<NBLK, 256, 0, stream>>>(cnt, blk);
    scan_top_kernel      <<<1, 512, 0, stream>>>(blk);
    scan_add_kernel      <<<NBLK, 256, 0, stream>>>(cnt, blk);
    place_kernel         <<<N_EDGES / 256, 256, 0, stream>>>(dst, enc, cnt, col);

    gather1_kernel       <<<N_NODES / 4, 256, 0, stream>>>(col, cnt, dis, x, xa);
    gemm1_kernel         <<<N_NODES / 32, 256, 0, stream>>>(xa, W1, b1);
    gemm2_kernel         <<<N_NODES / 16, 256, 0, stream>>>(xa, W2);
    gather2_lsm_kernel   <<<N_NODES / 16, 256, 0, stream>>>(col, cnt, dis, xa, b2, out);
}

// Round 6
// 340.003 us; speedup vs baseline: 3.1913x; 1.3803x over previous
//
#include <hip/hip_runtime.h>
#include <math.h>

#define N_NODES 100000
#define N_EDGES 1600000
#define NBLK 391   // ceil(100000/256)

typedef __attribute__((ext_vector_type(8))) short bf16x8;   // MFMA A/B frag (8 bf16)
typedef __attribute__((ext_vector_type(4))) float f32x4;    // MFMA C/D frag

__device__ __forceinline__ unsigned short f2bf(float f) {   // RNE fp32->bf16
    unsigned int u = __float_as_uint(f);
    u += 0x7FFF + ((u >> 16) & 1);
    return (unsigned short)(u >> 16);
}
__device__ __forceinline__ float bf_lo(unsigned int u) { return __uint_as_float(u << 16); }
__device__ __forceinline__ float bf_hi(unsigned int u) { return __uint_as_float(u & 0xFFFF0000u); }

// ---------------- CSR build: histogram(+rank) -> scan -> atomic-free place ----------------

__global__ __launch_bounds__(256) void zero_cnt_kernel(int* __restrict__ cnt) {
    int i = blockIdx.x * 256 + threadIdx.x;
    if (i < N_NODES) cnt[i] = 0;
}

// enc[e] = src | (rank<<17): src < 2^17, rank < 2^15 (max in-deg ~45 for Poisson(16)).
__global__ __launch_bounds__(256) void deg_count_rank_kernel(const int* __restrict__ src,
                                                             const int* __restrict__ dst,
                                                             int* __restrict__ cnt,
                                                             int* __restrict__ enc) {
    int e = blockIdx.x * 256 + threadIdx.x;
    if (e < N_EDGES) {
        int r = atomicAdd(&cnt[dst[e]], 1);
        enc[e] = src[e] | (r << 17);
    }
}

__global__ __launch_bounds__(256) void dis_kernel(const int* __restrict__ cnt,
                                                  float* __restrict__ dis) {
    int i = blockIdx.x * 256 + threadIdx.x;
    if (i < N_NODES) dis[i] = rsqrtf((float)cnt[i] + 1.0f);
}

__global__ __launch_bounds__(256) void scan_blk_kernel(int* __restrict__ cnt,
                                                       int* __restrict__ blk) {
    __shared__ int s[256];
    int t = threadIdx.x, i = blockIdx.x * 256 + t;
    int v = (i < N_NODES) ? cnt[i] : 0;
    s[t] = v;
    __syncthreads();
    for (int off = 1; off < 256; off <<= 1) {
        int u = (t >= off) ? s[t - off] : 0;
        __syncthreads();
        s[t] += u;
        __syncthreads();
    }
    if (i < N_NODES) cnt[i] = s[t] - v;
    if (t == 255) blk[blockIdx.x] = s[255];
}

__global__ __launch_bounds__(512) void scan_top_kernel(int* __restrict__ blk) {
    __shared__ int s[512];
    int t = threadIdx.x;
    int v = (t < NBLK) ? blk[t] : 0;
    s[t] = v;
    __syncthreads();
    for (int off = 1; off < 512; off <<= 1) {
        int u = (t >= off) ? s[t - off] : 0;
        __syncthreads();
        s[t] += u;
        __syncthreads();
    }
    if (t < NBLK) blk[t] = s[t] - v;
}

__global__ __launch_bounds__(256) void scan_add_kernel(int* __restrict__ cnt,
                                                       const int* __restrict__ blk) {
    int i = blockIdx.x * 256 + threadIdx.x;
    if (i < N_NODES) cnt[i] += blk[blockIdx.x];   // cnt[i] = start of node i
}

__global__ __launch_bounds__(256) void place_kernel(const int* __restrict__ dst,
                                                    const int* __restrict__ enc,
                                                    const int* __restrict__ start,
                                                    int* __restrict__ col) {
    int e = blockIdx.x * 256 + threadIdx.x;
    int d = dst[e];
    int v = enc[e];
    col[start[d] + (v >> 17)] = v & 0x1FFFF;
}

// ---------------- converts: x -> bf16, W1^T/W2^T -> bf16 ----------------

__global__ __launch_bounds__(256) void convert_x_kernel(const float* __restrict__ x,
                                                        ushort* __restrict__ xb) {
    int i = blockIdx.x * 256 + threadIdx.x;     // one float4 -> 4 bf16; 3.2M threads
    float4 v = *(const float4*)&x[i * 4];
    ushort4 o;
    o.x = f2bf(v.x); o.y = f2bf(v.y); o.z = f2bf(v.z); o.w = f2bf(v.w);
    *(ushort4*)&xb[i * 4] = o;
}

__global__ __launch_bounds__(256) void convert_w_kernel(const float* __restrict__ W1,
                                                        const float* __restrict__ W2,
                                                        ushort* __restrict__ W1T,
                                                        ushort* __restrict__ W2T) {
    int i = blockIdx.x * 256 + threadIdx.x;     // 72 blocks * 256 = 18432 exact
    if (i < 16384) {
        int k = i >> 7, n = i & 127;            // W1[k][n] -> W1T[n][k]
        W1T[n * 128 + k] = f2bf(W1[i]);
    } else {
        int j = i - 16384;                      // 2048 elements
        int k = j >> 4, n = j & 15;             // W2[k][n] -> W2T[n][k]
        W2T[n * 128 + k] = f2bf(W2[j]);
    }
}

// ---------------- layer-1 aggregation (bf16 rows, 8-deep MLP unroll) ----------------
// One wave per node; lane handles one dword (2 bf16 feats). Accumulate fp32, emit bf16.

__global__ __launch_bounds__(256) void gather1_kernel(const int* __restrict__ col,
                                                      const int* __restrict__ cnt,
                                                      const float* __restrict__ dis,
                                                      const unsigned int* __restrict__ xb,
                                                      unsigned int* __restrict__ xa) {
    int t = threadIdx.x;
    int node = blockIdx.x * 4 + (t >> 6);        // 25000 blocks * 4 = 100000 exact
    int lane = t & 63;
    float dn = dis[node];
    int beg = cnt[node];
    int end = (node == N_NODES - 1) ? N_EDGES : cnt[node + 1];
    unsigned int su = xb[node * 64 + lane];
    float a0x = bf_lo(su) * dn, a0y = bf_hi(su) * dn;
    float a1x = 0.f, a1y = 0.f, a2x = 0.f, a2y = 0.f, a3x = 0.f, a3y = 0.f;
    float a4x = 0.f, a4y = 0.f, a5x = 0.f, a5y = 0.f, a6x = 0.f, a6y = 0.f, a7x = 0.f, a7y = 0.f;
    int k = beg;
    for (; k + 8 <= end; k += 8) {
        int s0 = col[k], s1 = col[k + 1], s2 = col[k + 2], s3 = col[k + 3];
        int s4 = col[k + 4], s5 = col[k + 5], s6 = col[k + 6], s7 = col[k + 7];
        float w0 = dis[s0], w1 = dis[s1], w2 = dis[s2], w3 = dis[s3];
        float w4 = dis[s4], w5 = dis[s5], w6 = dis[s6], w7 = dis[s7];
        unsigned int u0 = xb[s0 * 64 + lane], u1 = xb[s1 * 64 + lane];
        unsigned int u2 = xb[s2 * 64 + lane], u3 = xb[s3 * 64 + lane];
        unsigned int u4 = xb[s4 * 64 + lane], u5 = xb[s5 * 64 + lane];
        unsigned int u6 = xb[s6 * 64 + lane], u7 = xb[s7 * 64 + lane];
        a0x += bf_lo(u0) * w0; a0y += bf_hi(u0) * w0;
        a1x += bf_lo(u1) * w1; a1y += bf_hi(u1) * w1;
        a2x += bf_lo(u2) * w2; a2y += bf_hi(u2) * w2;
        a3x += bf_lo(u3) * w3; a3y += bf_hi(u3) * w3;
        a4x += bf_lo(u4) * w4; a4y += bf_hi(u4) * w4;
        a5x += bf_lo(u5) * w5; a5y += bf_hi(u5) * w5;
        a6x += bf_lo(u6) * w6; a6y += bf_hi(u6) * w6;
        a7x += bf_lo(u7) * w7; a7y += bf_hi(u7) * w7;
    }
    for (; k + 4 <= end; k += 4) {
        int s0 = col[k], s1 = col[k + 1], s2 = col[k + 2], s3 = col[k + 3];
        float w0 = dis[s0], w1 = dis[s1], w2 = dis[s2], w3 = dis[s3];
        unsigned int u0 = xb[s0 * 64 + lane], u1 = xb[s1 * 64 + lane];
        unsigned int u2 = xb[s2 * 64 + lane], u3 = xb[s3 * 64 + lane];
        a0x += bf_lo(u0) * w0; a0y += bf_hi(u0) * w0;
        a1x += bf_lo(u1) * w1; a1y += bf_hi(u1) * w1;
        a2x += bf_lo(u2) * w2; a2y += bf_hi(u2) * w2;
        a3x += bf_lo(u3) * w3; a3y += bf_hi(u3) * w3;
    }
    for (; k < end; ++k) {
        int s = col[k];
        float w = dis[s];
        unsigned int u = xb[s * 64 + lane];
        a0x += bf_lo(u) * w; a0y += bf_hi(u) * w;
    }
    float rx = (((a0x + a1x) + (a2x + a3x)) + ((a4x + a5x) + (a6x + a7x))) * dn;
    float ry = (((a0y + a1y) + (a2y + a3y)) + ((a4y + a5y) + (a6y + a7y))) * dn;
    xa[node * 64 + lane] = (unsigned int)f2bf(rx) | ((unsigned int)f2bf(ry) << 16);
}

// ---------------- GEMM1 (MFMA bf16): h1 = relu(xa @ W1 + b1) ----------------
// 4 waves/block, 16 rows/wave, no LDS. A-frag: A[m=lane&15][k=quad*8+j] (16 B global).
// B-frag from W1T[n][k]: B[k][n=lane&15] (16 B global, L1-hot). D: col=lane&15, row=quad*4+r.

__global__ __launch_bounds__(256) void gemm1_mfma_kernel(const ushort* __restrict__ xa,
                                                         const ushort* __restrict__ W1T,
                                                         const float* __restrict__ b1,
                                                         ushort* __restrict__ h1) {
    int wave = threadIdx.x >> 6, lane = threadIdx.x & 63;
    int m0 = blockIdx.x * 64 + wave * 16;
    if (m0 >= N_NODES) return;                   // 100000 = 16*6250; last block partial
    int quad = lane >> 4;
    int row = m0 + (lane & 15);
    f32x4 acc[8] = {};
    for (int kk = 0; kk < 4; ++kk) {
        bf16x8 a = *(const bf16x8*)&xa[row * 128 + kk * 32 + quad * 8];
        #pragma unroll
        for (int nt = 0; nt < 8; ++nt) {
            bf16x8 b = *(const bf16x8*)&W1T[(nt * 16 + (lane & 15)) * 128 + kk * 32 + quad * 8];
            acc[nt] = __builtin_amdgcn_mfma_f32_16x16x32_bf16(a, b, acc[nt], 0, 0, 0);
        }
    }
    #pragma unroll
    for (int nt = 0; nt < 8; ++nt) {
        int n = nt * 16 + (lane & 15);
        float bias = b1[n];
        #pragma unroll
        for (int r = 0; r < 4; ++r) {
            int m = m0 + quad * 4 + r;
            h1[m * 128 + n] = f2bf(fmaxf(acc[nt][r] + bias, 0.0f));
        }
    }
}

// ---------------- GEMM2 (MFMA bf16): h2 = h1 @ W2 (dense 16-wide fp32 rows) ----------------

__global__ __launch_bounds__(256) void gemm2_mfma_kernel(const ushort* __restrict__ h1,
                                                         const ushort* __restrict__ W2T,
                                                         float* __restrict__ h2) {
    int wave = threadIdx.x >> 6, lane = threadIdx.x & 63;
    int m0 = blockIdx.x * 64 + wave * 16;
    if (m0 >= N_NODES) return;
    int quad = lane >> 4;
    int row = m0 + (lane & 15);
    f32x4 acc = {};
    #pragma unroll
    for (int kk = 0; kk < 4; ++kk) {
        bf16x8 a = *(const bf16x8*)&h1[row * 128 + kk * 32 + quad * 8];
        bf16x8 b = *(const bf16x8*)&W2T[(lane & 15) * 128 + kk * 32 + quad * 8];
        acc = __builtin_amdgcn_mfma_f32_16x16x32_bf16(a, b, acc, 0, 0, 0);
    }
    int n = lane & 15;
    #pragma unroll
    for (int r = 0; r < 4; ++r) h2[(m0 + quad * 4 + r) * 16 + n] = acc[r];
}

// ---------------- layer-2 gather + bias + log-softmax (dense h2 table) ----------------

__global__ __launch_bounds__(256) void gather2_lsm_kernel(const int* __restrict__ col,
                                                          const int* __restrict__ cnt,
                                                          const float* __restrict__ dis,
                                                          const float* __restrict__ h2,
                                                          const float* __restrict__ b2,
                                                          float* __restrict__ out) {
    int t = threadIdx.x;
    int node = blockIdx.x * 16 + (t >> 4);       // 6250 * 16 = 100000 exact
    int n = t & 15;
    float dn = dis[node];
    int beg = cnt[node];
    int end = (node == N_NODES - 1) ? N_EDGES : cnt[node + 1];
    float a0 = h2[node * 16 + n] * dn;           // self-loop term
    float a1 = 0.f, a2 = 0.f, a3 = 0.f, a4 = 0.f, a5 = 0.f, a6 = 0.f, a7 = 0.f;
    int k = beg;
    for (; k + 8 <= end; k += 8) {
        int s0 = col[k], s1 = col[k + 1], s2 = col[k + 2], s3 = col[k + 3];
        int s4 = col[k + 4], s5 = col[k + 5], s6 = col[k + 6], s7 = col[k + 7];
        a0 += h2[s0 * 16 + n] * dis[s0];
        a1 += h2[s1 * 16 + n] * dis[s1];
        a2 += h2[s2 * 16 + n] * dis[s2];
        a3 += h2[s3 * 16 + n] * dis[s3];
        a4 += h2[s4 * 16 + n] * dis[s4];
        a5 += h2[s5 * 16 + n] * dis[s5];
        a6 += h2[s6 * 16 + n] * dis[s6];
        a7 += h2[s7 * 16 + n] * dis[s7];
    }
    for (; k + 4 <= end; k += 4) {
        int s0 = col[k], s1 = col[k + 1], s2 = col[k + 2], s3 = col[k + 3];
        a0 += h2[s0 * 16 + n] * dis[s0];
        a1 += h2[s1 * 16 + n] * dis[s1];
        a2 += h2[s2 * 16 + n] * dis[s2];
        a3 += h2[s3 * 16 + n] * dis[s3];
    }
    for (; k < end; ++k) {
        int s = col[k];
        a0 += h2[s * 16 + n] * dis[s];
    }
    float acc = ((a0 + a1) + (a2 + a3)) + ((a4 + a5) + (a6 + a7));
    float v = acc * dn + b2[n];
    float m = v;
    #pragma unroll
    for (int off = 1; off < 16; off <<= 1) m = fmaxf(m, __shfl_xor(m, off, 16));
    float ssum = expf(v - m);
    #pragma unroll
    for (int off = 1; off < 16; off <<= 1) ssum += __shfl_xor(ssum, off, 16);
    out[node * 16 + n] = v - (m + logf(ssum));
}

// ---------------- launch ----------------

extern "C" void kernel_launch(void* const* d_in, const int* in_sizes, int n_in,
                              void* d_out, int out_size, void* d_ws, size_t ws_size,
                              hipStream_t stream) {
    const float* x  = (const float*)d_in[0];
    const int*   ei = (const int*)d_in[1];
    const float* W1 = (const float*)d_in[2];
    const float* b1 = (const float*)d_in[3];
    const float* W2 = (const float*)d_in[4];
    const float* b2 = (const float*)d_in[5];
    float* out = (float*)d_out;

    const int* src = ei;              // edge_index[0]
    const int* dst = ei + N_EDGES;    // edge_index[1]

    // workspace (bytes), TOTAL = 58,440,960 (~58.44 MB; 58.4 MB proven safe R2-R5).
    // Time-shared aliases:
    //   offset 0:        enc (CSR build) -> xb bf16 (gather1 in) -> h1 bf16 (gemm1 out)
    //   offset 25.6 MB:  xa bf16 (gather1 out, gemm1 in) -> h2 fp32 (gemm2 out)
    char* ws = (char*)d_ws;
    int*    enc = (int*)   (ws + 0);            //  6,400,000
    ushort* xb  = (ushort*)(ws + 0);            // 25,600,000
    ushort* h1  = (ushort*)(ws + 0);            // 25,600,000
    ushort* xa  = (ushort*)(ws + 25600000);     // 25,600,000
    float*  h2  = (float*) (ws + 25600000);     //  6,400,000
    int*    col = (int*)   (ws + 51200000);     //  6,400,000
    float*  dis = (float*) (ws + 57600000);     //    400,000
    int*    cnt = (int*)   (ws + 58000000);     //    400,000
    int*    blk = (int*)   (ws + 58400000);     //      1,564
    ushort* W1T = (ushort*)(ws + 58404096);     //     32,768
    ushort* W2T = (ushort*)(ws + 58436864);     //      4,096

    zero_cnt_kernel      <<<NBLK, 256, 0, stream>>>(cnt);
    deg_count_rank_kernel<<<N_EDGES / 256, 256, 0, stream>>>(src, dst, cnt, enc);
    dis_kernel           <<<NBLK, 256, 0, stream>>>(cnt, dis);
    scan_blk_kernel      <<<NBLK, 256, 0, stream>>>(cnt, blk);
    scan_top_kernel      <<<1, 512, 0, stream>>>(blk);
    scan_add_kernel      <<<NBLK, 256, 0, stream>>>(cnt, blk);
    place_kernel         <<<N_EDGES / 256, 256, 0, stream>>>(dst, enc, cnt, col);

    convert_x_kernel     <<<N_NODES * 128 / 4 / 256, 256, 0, stream>>>(x, xb);  // after place (enc dead)
    convert_w_kernel     <<<72, 256, 0, stream>>>(W1, W2, W1T, W2T);

    gather1_kernel       <<<N_NODES / 4, 256, 0, stream>>>(col, cnt, dis, (const unsigned int*)xb,
                                                           (unsigned int*)xa);
    gemm1_mfma_kernel    <<<1563, 256, 0, stream>>>(xa, W1T, b1, h1);   // h1 overwrites dead xb
    gemm2_mfma_kernel    <<<1563, 256, 0, stream>>>(h1, W2T, h2);       // h2 overwrites dead xa
    gather2_lsm_kernel   <<<N_NODES / 16, 256, 0, stream>>>(col, cnt, dis, h2, b2, out);
}

// Round 7
// 325.863 us; speedup vs baseline: 3.3297x; 1.0434x over previous
//
#include <hip/hip_runtime.h>
#include <math.h>

#define N_NODES 100000
#define N_EDGES 1600000
#define NBLK 391   // ceil(100000/256)

typedef __attribute__((ext_vector_type(8))) short bf16x8;   // MFMA A/B frag (8 bf16)
typedef __attribute__((ext_vector_type(4))) float f32x4;    // MFMA C/D frag

__device__ __forceinline__ unsigned short f2bf(float f) {   // RNE fp32->bf16
    unsigned int u = __float_as_uint(f);
    u += 0x7FFF + ((u >> 16) & 1);
    return (unsigned short)(u >> 16);
}
__device__ __forceinline__ float bf_lo(unsigned int u) { return __uint_as_float(u << 16); }
__device__ __forceinline__ float bf_hi(unsigned int u) { return __uint_as_float(u & 0xFFFF0000u); }

// ---------------- CSR build ----------------

__global__ __launch_bounds__(256) void zero_cnt_kernel(int* __restrict__ cnt) {
    int i = blockIdx.x * 256 + threadIdx.x;
    if (i < N_NODES) cnt[i] = 0;
}

// enc[e] = src | (rank<<17): src < 2^17, rank < 2^15 (max in-deg ~45 for Poisson(16)).
__global__ __launch_bounds__(256) void deg_count_rank_kernel(const int* __restrict__ src,
                                                             const int* __restrict__ dst,
                                                             int* __restrict__ cnt,
                                                             int* __restrict__ enc) {
    int e = blockIdx.x * 256 + threadIdx.x;
    if (e < N_EDGES) {
        int r = atomicAdd(&cnt[dst[e]], 1);
        enc[e] = src[e] | (r << 17);
    }
}

// Fused: dis[i] = rsqrt(deg+1), then per-block exclusive scan of cnt (+ block totals).
__global__ __launch_bounds__(256) void scan_blk_dis_kernel(int* __restrict__ cnt,
                                                           int* __restrict__ blk,
                                                           float* __restrict__ dis) {
    __shared__ int s[256];
    int t = threadIdx.x, i = blockIdx.x * 256 + t;
    int v = (i < N_NODES) ? cnt[i] : 0;
    if (i < N_NODES) dis[i] = rsqrtf((float)v + 1.0f);
    s[t] = v;
    __syncthreads();
    for (int off = 1; off < 256; off <<= 1) {
        int u = (t >= off) ? s[t - off] : 0;
        __syncthreads();
        s[t] += u;
        __syncthreads();
    }
    if (i < N_NODES) cnt[i] = s[t] - v;           // exclusive within block
    if (t == 255) blk[blockIdx.x] = s[255];
}

__global__ __launch_bounds__(512) void scan_top_kernel(int* __restrict__ blk) {
    __shared__ int s[512];
    int t = threadIdx.x;
    int v = (t < NBLK) ? blk[t] : 0;
    s[t] = v;
    __syncthreads();
    for (int off = 1; off < 512; off <<= 1) {
        int u = (t >= off) ? s[t - off] : 0;
        __syncthreads();
        s[t] += u;
        __syncthreads();
    }
    if (t < NBLK) blk[t] = s[t] - v;
}

// start(d) = cnt[d] + blk[d>>8]  (scan_add folded in). Atomic-free placement.
__global__ __launch_bounds__(256) void place_kernel(const int* __restrict__ dst,
                                                    const int* __restrict__ enc,
                                                    const int* __restrict__ cnt,
                                                    const int* __restrict__ blk,
                                                    int* __restrict__ col) {
    int e = blockIdx.x * 256 + threadIdx.x;
    int d = dst[e];
    int v = enc[e];
    col[cnt[d] + blk[d >> 8] + (v >> 17)] = v & 0x1FFFF;
}

// ---------------- converts (fused x + W1T + W2T) ----------------

__global__ __launch_bounds__(256) void convert_xw_kernel(const float* __restrict__ x,
                                                         const float* __restrict__ W1,
                                                         const float* __restrict__ W2,
                                                         ushort* __restrict__ xb,
                                                         ushort* __restrict__ W1T,
                                                         ushort* __restrict__ W2T) {
    if (blockIdx.x < 12500) {
        int i = blockIdx.x * 256 + threadIdx.x;
        float4 v = *(const float4*)&x[i * 4];
        ushort4 o;
        o.x = f2bf(v.x); o.y = f2bf(v.y); o.z = f2bf(v.z); o.w = f2bf(v.w);
        *(ushort4*)&xb[i * 4] = o;
    } else {
        int j = (blockIdx.x - 12500) * 256 + threadIdx.x;   // 72 blocks * 256 = 18432
        if (j < 16384) {
            int k = j >> 7, n = j & 127;                     // W1[k][n] -> W1T[n][k]
            W1T[n * 128 + k] = f2bf(W1[j]);
        } else {
            int q = j - 16384;                               // 2048 elements
            int k = q >> 4, n = q & 15;                      // W2[k][n] -> W2T[n][k]
            W2T[n * 128 + k] = f2bf(W2[q]);
        }
    }
}

// ---------------- layer-1 aggregation (bf16 rows, 8-deep MLP unroll) ----------------

__global__ __launch_bounds__(256) void gather1_kernel(const int* __restrict__ col,
                                                      const int* __restrict__ cnt,
                                                      const int* __restrict__ blk,
                                                      const float* __restrict__ dis,
                                                      const unsigned int* __restrict__ xb,
                                                      unsigned int* __restrict__ xa) {
    int t = threadIdx.x;
    int node = blockIdx.x * 4 + (t >> 6);        // 25000 blocks * 4 = 100000 exact
    int lane = t & 63;
    float dn = dis[node];
    int beg = cnt[node] + blk[node >> 8];
    int end = (node == N_NODES - 1) ? N_EDGES : cnt[node + 1] + blk[(node + 1) >> 8];
    unsigned int su = xb[node * 64 + lane];
    float a0x = bf_lo(su) * dn, a0y = bf_hi(su) * dn;
    float a1x = 0.f, a1y = 0.f, a2x = 0.f, a2y = 0.f, a3x = 0.f, a3y = 0.f;
    float a4x = 0.f, a4y = 0.f, a5x = 0.f, a5y = 0.f, a6x = 0.f, a6y = 0.f, a7x = 0.f, a7y = 0.f;
    int k = beg;
    for (; k + 8 <= end; k += 8) {
        int s0 = col[k], s1 = col[k + 1], s2 = col[k + 2], s3 = col[k + 3];
        int s4 = col[k + 4], s5 = col[k + 5], s6 = col[k + 6], s7 = col[k + 7];
        float w0 = dis[s0], w1 = dis[s1], w2 = dis[s2], w3 = dis[s3];
        float w4 = dis[s4], w5 = dis[s5], w6 = dis[s6], w7 = dis[s7];
        unsigned int u0 = xb[s0 * 64 + lane], u1 = xb[s1 * 64 + lane];
        unsigned int u2 = xb[s2 * 64 + lane], u3 = xb[s3 * 64 + lane];
        unsigned int u4 = xb[s4 * 64 + lane], u5 = xb[s5 * 64 + lane];
        unsigned int u6 = xb[s6 * 64 + lane], u7 = xb[s7 * 64 + lane];
        a0x += bf_lo(u0) * w0; a0y += bf_hi(u0) * w0;
        a1x += bf_lo(u1) * w1; a1y += bf_hi(u1) * w1;
        a2x += bf_lo(u2) * w2; a2y += bf_hi(u2) * w2;
        a3x += bf_lo(u3) * w3; a3y += bf_hi(u3) * w3;
        a4x += bf_lo(u4) * w4; a4y += bf_hi(u4) * w4;
        a5x += bf_lo(u5) * w5; a5y += bf_hi(u5) * w5;
        a6x += bf_lo(u6) * w6; a6y += bf_hi(u6) * w6;
        a7x += bf_lo(u7) * w7; a7y += bf_hi(u7) * w7;
    }
    for (; k + 4 <= end; k += 4) {
        int s0 = col[k], s1 = col[k + 1], s2 = col[k + 2], s3 = col[k + 3];
        float w0 = dis[s0], w1 = dis[s1], w2 = dis[s2], w3 = dis[s3];
        unsigned int u0 = xb[s0 * 64 + lane], u1 = xb[s1 * 64 + lane];
        unsigned int u2 = xb[s2 * 64 + lane], u3 = xb[s3 * 64 + lane];
        a0x += bf_lo(u0) * w0; a0y += bf_hi(u0) * w0;
        a1x += bf_lo(u1) * w1; a1y += bf_hi(u1) * w1;
        a2x += bf_lo(u2) * w2; a2y += bf_hi(u2) * w2;
        a3x += bf_lo(u3) * w3; a3y += bf_hi(u3) * w3;
    }
    for (; k < end; ++k) {
        int s = col[k];
        float w = dis[s];
        unsigned int u = xb[s * 64 + lane];
        a0x += bf_lo(u) * w; a0y += bf_hi(u) * w;
    }
    float rx = (((a0x + a1x) + (a2x + a3x)) + ((a4x + a5x) + (a6x + a7x))) * dn;
    float ry = (((a0y + a1y) + (a2y + a3y)) + ((a4y + a5y) + (a6y + a7y))) * dn;
    xa[node * 64 + lane] = (unsigned int)f2bf(rx) | ((unsigned int)f2bf(ry) << 16);
}

// ---------------- fused MLP: h2 = relu(xa@W1 + b1) @ W2, h2 emitted as bf16 ----------------
// 4 waves/block, 16 rows/wave. Layer1: A from global (A[m=lane&15][k=quad*8+j]),
// B from W1T (L1-hot). h1 (D-layout: col=lane&15,row=quad*4+r) -> LDS -> A-layout for layer2.

__global__ __launch_bounds__(256) void mlp_kernel(const ushort* __restrict__ xa,
                                                  const ushort* __restrict__ W1T,
                                                  const float* __restrict__ b1,
                                                  const ushort* __restrict__ W2T,
                                                  ushort* __restrict__ h2b) {
    __shared__ ushort sh[4][16][136];   // 136: keeps ds_read_b128 16B-aligned, banks spread
    int t = threadIdx.x;
    int wave = t >> 6, lane = t & 63;
    int l = lane & 15, quad = lane >> 4;
    int m0 = blockIdx.x * 64 + wave * 16;        // 1563*64 = 100032; waves past end idle
    bool valid = (m0 < N_NODES);                 // whole-wave predicate (no early return!)
    int row = valid ? (m0 + l) : 0;

    f32x4 acc[8] = {};
    #pragma unroll
    for (int kk = 0; kk < 4; ++kk) {
        bf16x8 a = *(const bf16x8*)&xa[row * 128 + kk * 32 + quad * 8];
        #pragma unroll
        for (int nt = 0; nt < 8; ++nt) {
            bf16x8 b = *(const bf16x8*)&W1T[(nt * 16 + l) * 128 + kk * 32 + quad * 8];
            acc[nt] = __builtin_amdgcn_mfma_f32_16x16x32_bf16(a, b, acc[nt], 0, 0, 0);
        }
    }
    #pragma unroll
    for (int nt = 0; nt < 8; ++nt) {
        float bias = b1[nt * 16 + l];
        #pragma unroll
        for (int r = 0; r < 4; ++r)
            sh[wave][quad * 4 + r][nt * 16 + l] = f2bf(fmaxf(acc[nt][r] + bias, 0.0f));
    }
    __syncthreads();   // all waves present (no early return) — orders LDS writes->reads

    f32x4 acc2 = {};
    #pragma unroll
    for (int kk = 0; kk < 4; ++kk) {
        bf16x8 a2 = *(const bf16x8*)&sh[wave][l][kk * 32 + quad * 8];
        bf16x8 bw = *(const bf16x8*)&W2T[l * 128 + kk * 32 + quad * 8];
        acc2 = __builtin_amdgcn_mfma_f32_16x16x32_bf16(a2, bw, acc2, 0, 0, 0);
    }
    if (valid) {
        #pragma unroll
        for (int r = 0; r < 4; ++r)
            h2b[(m0 + quad * 4 + r) * 16 + l] = f2bf(acc2[r]);   // h2[m][n=l]
    }
}

// ---------------- layer-2 gather + bias + log-softmax (bf16 h2 table, 8 lanes/node) ----------------

__global__ __launch_bounds__(256) void gather2_lsm_kernel(const int* __restrict__ col,
                                                          const int* __restrict__ cnt,
                                                          const int* __restrict__ blk,
                                                          const float* __restrict__ dis,
                                                          const unsigned int* __restrict__ h2p,
                                                          const float* __restrict__ b2,
                                                          float* __restrict__ out) {
    int t = threadIdx.x;
    int node = blockIdx.x * 32 + (t >> 3);       // 3125 * 32 = 100000 exact
    int c = t & 7;                               // class pair: (2c, 2c+1)
    float dn = dis[node];
    int beg = cnt[node] + blk[node >> 8];
    int end = (node == N_NODES - 1) ? N_EDGES : cnt[node + 1] + blk[(node + 1) >> 8];
    unsigned int su = h2p[node * 8 + c];
    float a0x = bf_lo(su) * dn, a0y = bf_hi(su) * dn;    // self-loop term
    float a1x = 0.f, a1y = 0.f, a2x = 0.f, a2y = 0.f, a3x = 0.f, a3y = 0.f;
    int k = beg;
    for (; k + 4 <= end; k += 4) {
        int s0 = col[k], s1 = col[k + 1], s2 = col[k + 2], s3 = col[k + 3];
        float w0 = dis[s0], w1 = dis[s1], w2 = dis[s2], w3 = dis[s3];
        unsigned int u0 = h2p[s0 * 8 + c], u1 = h2p[s1 * 8 + c];
        unsigned int u2 = h2p[s2 * 8 + c], u3 = h2p[s3 * 8 + c];
        a0x += bf_lo(u0) * w0; a0y += bf_hi(u0) * w0;
        a1x += bf_lo(u1) * w1; a1y += bf_hi(u1) * w1;
        a2x += bf_lo(u2) * w2; a2y += bf_hi(u2) * w2;
        a3x += bf_lo(u3) * w3; a3y += bf_hi(u3) * w3;
    }
    for (; k < end; ++k) {
        int s = col[k];
        float w = dis[s];
        unsigned int u = h2p[s * 8 + c];
        a0x += bf_lo(u) * w; a0y += bf_hi(u) * w;
    }
    float2 bb = ((const float2*)b2)[c];
    float v0 = ((a0x + a1x) + (a2x + a3x)) * dn + bb.x;
    float v1 = ((a0y + a1y) + (a2y + a3y)) * dn + bb.y;
    float m = fmaxf(v0, v1);
    #pragma unroll
    for (int off = 1; off < 8; off <<= 1) m = fmaxf(m, __shfl_xor(m, off, 8));
    float ssum = expf(v0 - m) + expf(v1 - m);
    #pragma unroll
    for (int off = 1; off < 8; off <<= 1) ssum += __shfl_xor(ssum, off, 8);
    float lg = m + logf(ssum);
    ((float2*)out)[node * 8 + c] = make_float2(v0 - lg, v1 - lg);
}

// ---------------- launch ----------------

extern "C" void kernel_launch(void* const* d_in, const int* in_sizes, int n_in,
                              void* d_out, int out_size, void* d_ws, size_t ws_size,
                              hipStream_t stream) {
    const float* x  = (const float*)d_in[0];
    const int*   ei = (const int*)d_in[1];
    const float* W1 = (const float*)d_in[2];
    const float* b1 = (const float*)d_in[3];
    const float* W2 = (const float*)d_in[4];
    const float* b2 = (const float*)d_in[5];
    float* out = (float*)d_out;

    const int* src = ei;              // edge_index[0]
    const int* dst = ei + N_EDGES;    // edge_index[1]

    // workspace (bytes), TOTAL = 58,440,960 (unchanged, proven safe R2-R6).
    // offset 0 timeline: enc (CSR) -> xb bf16 (convert->gather1) -> h2b bf16 (mlp->gather2)
    char* ws = (char*)d_ws;
    int*    enc = (int*)   (ws + 0);            //  6,400,000
    ushort* xb  = (ushort*)(ws + 0);            // 25,600,000
    ushort* h2b = (ushort*)(ws + 0);            //  3,200,000
    ushort* xa  = (ushort*)(ws + 25600000);     // 25,600,000
    int*    col = (int*)   (ws + 51200000);     //  6,400,000
    float*  dis = (float*) (ws + 57600000);     //    400,000
    int*    cnt = (int*)   (ws + 58000000);     //    400,000
    int*    blk = (int*)   (ws + 58400000);     //      1,564
    ushort* W1T = (ushort*)(ws + 58404096);     //     32,768
    ushort* W2T = (ushort*)(ws + 58436864);     //      4,096

    zero_cnt_kernel      <<<NBLK, 256, 0, stream>>>(cnt);
    deg_count_rank_kernel<<<N_EDGES / 256, 256, 0, stream>>>(src, dst, cnt, enc);
    scan_blk_dis_kernel  <<<NBLK, 256, 0, stream>>>(cnt, blk, dis);
    scan_top_kernel      <<<1, 512, 0, stream>>>(blk);
    place_kernel         <<<N_EDGES / 256, 256, 0, stream>>>(dst, enc, cnt, blk, col);

    convert_xw_kernel    <<<12572, 256, 0, stream>>>(x, W1, W2, xb, W1T, W2T);  // after place (enc dead)

    gather1_kernel       <<<N_NODES / 4, 256, 0, stream>>>(col, cnt, blk, dis,
                                                           (const unsigned int*)xb,
                                                           (unsigned int*)xa);
    mlp_kernel           <<<1563, 256, 0, stream>>>(xa, W1T, b1, W2T, h2b);     // h2b overwrites dead xb
    gather2_lsm_kernel   <<<3125, 256, 0, stream>>>(col, cnt, blk, dis,
                                                    (const unsigned int*)h2b, b2, out);
}